// Round 11
// baseline (36.210 us; speedup 1.0000x reference)
//
#include <hip/hip_runtime.h>
#include <math.h>

#define THRESH_ 0.95f

typedef __attribute__((ext_vector_type(8))) short short8v;
typedef __attribute__((ext_vector_type(16))) float f32x16;

__device__ __forceinline__ unsigned short f2bf_rne(float x) {
    unsigned u = __float_as_uint(x);
    u += 0x7fffu + ((u >> 16) & 1u);
    return (unsigned short)(u >> 16);
}

// Single fused kernel: vocab prep + MFMA-screened select + haar + output assembly.
// One block per batch row. Vocab stats are recomputed per block (1024 threads x
// 1 word each, ~50 VALU) straight into LDS — no k0, no workspace round-trip.
__global__ __launch_bounds__(1024) void k12_fused(const float* __restrict__ X,
                                                  const float* __restrict__ vocab,
                                                  const float* __restrict__ word_emb,
                                                  const float* __restrict__ haar_emb,
                                                  const float* __restrict__ pos_emb,
                                                  float* __restrict__ out) {
    __shared__ float4  wcl4[2048];    // fp32 centered vocab (32 KB)
    __shared__ short8v wcb_lds[1024]; // bf16 vocab (16 KB)
    __shared__ float   wsl[1024];     // word stds (4 KB)
    __shared__ float   xrow[1024];    // 4 KB
    __shared__ float   segf[1024];    // fp32 centered segments [128][8] (4 KB)
    __shared__ short8v segb[128];     // bf16 segments (2 KB)
    __shared__ float   sstd_l[128];
    __shared__ float   thr_l[128];    // 7.52f * sstd
    __shared__ float   stb[512];      // [4 chunks][128 segs]
    __shared__ int     sti[512];
    __shared__ float   stm[512];
    __shared__ float   tree[254];
    __shared__ float   hc_lds[1024];  // [128][8]
    __shared__ int     idx_lds[128];

    int t = threadIdx.x;
    int b = blockIdx.x;

    // ---- staging: X row + per-word vocab stats (identical arithmetic to old k0) ----
    xrow[t] = X[b * 1024 + t];
    {
        const float4* v4 = (const float4*)vocab + t * 2;
        float4 a = v4[0], bb = v4[1];
        float w[8] = {a.x, a.y, a.z, a.w, bb.x, bb.y, bb.z, bb.w};
        float s = 0.f;
#pragma unroll
        for (int c = 0; c < 8; c++) s += w[c];
        float mean = s * 0.125f;
        float ss = 0.f;
        float wcv[8];
#pragma unroll
        for (int c = 0; c < 8; c++) { wcv[c] = w[c] - mean; ss += wcv[c] * wcv[c]; }
        float sd = sqrtf(ss * 0.125f);
        float4 o0 = {wcv[0], wcv[1], wcv[2], wcv[3]};
        float4 o1 = {wcv[4], wcv[5], wcv[6], wcv[7]};
        wcl4[t * 2] = o0;
        wcl4[t * 2 + 1] = o1;
        wsl[t] = sd;
        union { uint4 q; unsigned short u[8]; } pk;
#pragma unroll
        for (int c = 0; c < 8; c++) pk.u[c] = f2bf_rne(wcv[c]);
        ((uint4*)wcb_lds)[t] = pk.q;
    }
    if (t < 512) { stb[t] = -INFINITY; sti[t] = -1; stm[t] = 0.f; }
    __syncthreads();

    // ---- segment stats (t < 128 only) ----
    if (t < 128) {
        float seg[8];
#pragma unroll
        for (int c = 0; c < 8; c++) seg[c] = xrow[t * 8 + c];
        float sum = 0.f;
#pragma unroll
        for (int c = 0; c < 8; c++) sum += seg[c];
        float mean = sum * 0.125f;
        float segc[8];
        float ss = 0.f;
#pragma unroll
        for (int c = 0; c < 8; c++) { segc[c] = seg[c] - mean; ss += segc[c] * segc[c]; }
        float sstd = sqrtf(ss * 0.125f);
        union { short8v v; unsigned short u[8]; } pk;
#pragma unroll
        for (int c = 0; c < 8; c++) { segf[t * 8 + c] = segc[c]; pk.u[c] = f2bf_rne(segc[c]); }
        segb[t] = pk.v;
        sstd_l[t] = sstd;
        thr_l[t] = 7.52f * sstd;
        tree[t] = sum;
    }
    __syncthreads();

    // ---- MFMA screen ----
    // Screen |acc_bf16| > 7.52*sstd*wsd has no false negatives vs the exact
    // condition |dot| >= 7.6000000238*RN(wsd*sstd) (bf16 error <= 0.032*sstd*wsd).
    // Rare candidates: exact fp32 dot (same op order as earlier rounds) +
    // f64 MID test + IEEE divide, applied in v-order per (chunk, segment).
    int w = t >> 6, lane = t & 63;
    {
        int sb = w & 3;        // seg-block (32 segments)
        int g = w >> 2;        // word-group (chunk): words [g*256, g*256+256)
        int half = lane >> 5;

        short8v af = {0, 0, 0, 0, 0, 0, 0, 0};
        if (lane < 32) af = segb[sb * 32 + lane];

        float thr_r[16];
#pragma unroll
        for (int i = 0; i < 16; i++) {
            int row = (i & 3) + 8 * (i >> 2) + 4 * half;
            thr_r[i] = thr_l[sb * 32 + row];
        }

        const double MID = 0x1.E66667p-1;
        for (int j = 0; j < 8; j++) {
            int wb = g * 8 + j;
            short8v bf = {0, 0, 0, 0, 0, 0, 0, 0};
            if (lane < 32) bf = wcb_lds[wb * 32 + lane];
            float wsd_c = wsl[wb * 32 + (lane & 31)];

            f32x16 accz = {0.f, 0.f, 0.f, 0.f, 0.f, 0.f, 0.f, 0.f,
                           0.f, 0.f, 0.f, 0.f, 0.f, 0.f, 0.f, 0.f};
            f32x16 acc = __builtin_amdgcn_mfma_f32_32x32x16_bf16(af, bf, accz, 0, 0, 0);

            bool anyp = false;
#pragma unroll
            for (int i = 0; i < 16; i++) anyp |= (fabsf(acc[i]) > thr_r[i] * wsd_c);

            if (__builtin_expect(anyp, 0)) {
#pragma unroll
                for (int i = 0; i < 16; i++) {
                    unsigned long long mi = __ballot(fabsf(acc[i]) > thr_r[i] * wsd_c);
                    while (mi) {
                        int src = __builtin_ctzll(mi);
                        mi &= mi - 1;
                        if (lane == src) {
                            int col = src & 31;
                            int seg_r = sb * 32 + (i & 3) + 8 * (i >> 2) + 4 * (src >> 5);
                            int v = wb * 32 + col;
                            float sst = sstd_l[seg_r];
                            float wsd = wsl[v];
                            const float* sc = &segf[seg_r * 8];
                            float4 wa = wcl4[v * 2];
                            float4 wbv = wcl4[v * 2 + 1];
                            // EXACT mul/fma order of previous rounds
                            float dot = sc[0] * wa.x + sc[1] * wa.y + sc[2] * wa.z + sc[3] * wa.w
                                      + sc[4] * wbv.x + sc[5] * wbv.y + sc[6] * wbv.z + sc[7] * wbv.w;
                            float cov = dot * 0.125f;
                            float denom = wsd * sst;
                            if ((double)fabsf(cov) >= MID * (double)denom) {
                                float c = (denom == 0.f) ? 0.f : cov / denom;
                                float a = fabsf(c);
                                int sidx = g * 128 + seg_r;
                                stm[sidx] = fmaxf(stm[sidx], a);
                                if (a > THRESH_ && stb[sidx] < a) { stb[sidx] = c; sti[sidx] = v; }
                            }
                        }
                    }
                }
            }
        }
    }
    __syncthreads();

    // ---- haar sum tree ----
    if (t < 64) tree[128 + t] = tree[2 * t] + tree[2 * t + 1];
    __syncthreads();
    if (t < 32) tree[192 + t] = tree[128 + 2 * t] + tree[128 + 2 * t + 1];
    __syncthreads();
    if (t < 16) tree[224 + t] = tree[192 + 2 * t] + tree[192 + 2 * t + 1];
    __syncthreads();
    if (t < 8) tree[240 + t] = tree[224 + 2 * t] + tree[224 + 2 * t + 1];
    __syncthreads();
    if (t < 4) tree[248 + t] = tree[240 + 2 * t] + tree[240 + 2 * t + 1];
    __syncthreads();
    if (t < 2) tree[252 + t] = tree[248 + 2 * t] + tree[248 + 2 * t + 1];
    __syncthreads();

    // ---- ordered 4-chunk merge + haar coefficients (t < 128) ----
    if (t < 128) {
        float Bb = stb[t];
        int I = sti[t];
#pragma unroll
        for (int p = 1; p < 4; p++) {
            float yb = stb[p * 128 + t];
            int yi = sti[p * 128 + t];
            float ym = stm[p * 128 + t];
            bool take = (yi != -1) && (!(Bb > THRESH_) || (ym > Bb));
            if (take) { Bb = yb; I = yi; }
        }
        float mask = (I >= 0) ? 1.f : 0.f;

        const int base[7] = {252, 248, 240, 224, 192, 128, 0};
        const float scl[7] = {0.03125f, 0.04419417382415922f, 0.0625f,
                              0.08838834764831843f, 0.125f,
                              0.17677669529663687f, 0.25f};
        float hcv[8];
#pragma unroll
        for (int l = 0; l < 7; l++) {
            int j = (t << l) >> 7;
            hcv[l] = scl[l] * (tree[base[l] + 2 * j] - tree[base[l] + 2 * j + 1]);
        }
        float s4a = xrow[t * 8 + 0] + xrow[t * 8 + 1] + xrow[t * 8 + 2] + xrow[t * 8 + 3];
        float s4b = xrow[t * 8 + 4] + xrow[t * 8 + 5] + xrow[t * 8 + 6] + xrow[t * 8 + 7];
        hcv[7] = 0.3535533905932738f * (s4a - s4b);

#pragma unroll
        for (int l = 0; l < 8; l++) hc_lds[t * 8 + l] = hcv[l] * mask;
        idx_lds[t] = I;
    }
    __syncthreads();

    // ---- phase 2: output assembly (plain stores — NT reverted) ----
    if (w < 12) {
        int third = w % 3;
        int grp = w / 3;
        int c = third * 64 + lane;

        float4 he[8];
        const float4* hg = (const float4*)haar_emb;
#pragma unroll
        for (int l = 0; l < 8; l++) he[l] = hg[l * 192 + c];

        const float4* pos4 = (const float4*)pos_emb;
        const float4* we4 = (const float4*)word_emb;
        float4* out4 = (float4*)out + (size_t)b * 128 * 192;

        for (int k = 0; k < 32; k += 2) {
            int row0 = grp * 32 + k;
            int row1 = row0 + 1;
            int iv0 = idx_lds[row0];
            int iv1 = idx_lds[row1];
            int ivc0 = iv0 < 0 ? 0 : iv0;
            int ivc1 = iv1 < 0 ? 0 : iv1;
            float msk0 = iv0 < 0 ? 0.f : 1.f;
            float msk1 = iv1 < 0 ? 0.f : 1.f;
            float4 p0 = pos4[row0 * 192 + c];
            float4 w0 = we4[(size_t)ivc0 * 192 + c];
            float4 h0a = *(const float4*)&hc_lds[row0 * 8];
            float4 h0b = *(const float4*)&hc_lds[row0 * 8 + 4];
            float4 p1 = pos4[row1 * 192 + c];
            float4 w1 = we4[(size_t)ivc1 * 192 + c];
            float4 h1a = *(const float4*)&hc_lds[row1 * 8];
            float4 h1b = *(const float4*)&hc_lds[row1 * 8 + 4];

            float4 acc0;
            acc0.x = fmaf(w0.x, msk0, p0.x);
            acc0.y = fmaf(w0.y, msk0, p0.y);
            acc0.z = fmaf(w0.z, msk0, p0.z);
            acc0.w = fmaf(w0.w, msk0, p0.w);
            float h0[8] = {h0a.x, h0a.y, h0a.z, h0a.w, h0b.x, h0b.y, h0b.z, h0b.w};
#pragma unroll
            for (int l = 0; l < 8; l++) {
                acc0.x += h0[l] * he[l].x;
                acc0.y += h0[l] * he[l].y;
                acc0.z += h0[l] * he[l].z;
                acc0.w += h0[l] * he[l].w;
            }
            out4[row0 * 192 + c] = acc0;

            float4 acc1;
            acc1.x = fmaf(w1.x, msk1, p1.x);
            acc1.y = fmaf(w1.y, msk1, p1.y);
            acc1.z = fmaf(w1.z, msk1, p1.z);
            acc1.w = fmaf(w1.w, msk1, p1.w);
            float h1[8] = {h1a.x, h1a.y, h1a.z, h1a.w, h1b.x, h1b.y, h1b.z, h1b.w};
#pragma unroll
            for (int l = 0; l < 8; l++) {
                acc1.x += h1[l] * he[l].x;
                acc1.y += h1[l] * he[l].y;
                acc1.z += h1[l] * he[l].z;
                acc1.w += h1[l] * he[l].w;
            }
            out4[row1 * 192 + c] = acc1;
        }
    }
}

extern "C" void kernel_launch(void* const* d_in, const int* in_sizes, int n_in,
                              void* d_out, int out_size, void* d_ws, size_t ws_size,
                              hipStream_t stream) {
    const float* X        = (const float*)d_in[0];
    const float* vocab    = (const float*)d_in[1];
    const float* word_emb = (const float*)d_in[2];
    const float* haar_emb = (const float*)d_in[3];
    const float* pos_emb  = (const float*)d_in[4];
    float* out = (float*)d_out;

    hipLaunchKernelGGL(k12_fused, dim3(256), dim3(1024), 0, stream,
                       X, vocab, word_emb, haar_emb, pos_emb, out);
}